// Round 4
// baseline (1364.641 us; speedup 1.0000x reference)
//
#include <hip/hip_runtime.h>

#define N_ROWS 131072
#define DIM 64
#define K_CODES 4096

#define BM 64                      // rows per block (block owns all 4096 codes)
#define CK 64                      // codes per LDS chunk
#define NCHUNK (K_CODES / CK)      // 64 chunks
#define XST 68                     // LDS stride (64 + 4 pad) -> 2-way banks max
#define EST 68

// order-preserving float -> uint32 (min over keys == min over floats)
__device__ inline unsigned int fkey(float f) {
    unsigned int u = __float_as_uint(f);
    return (u & 0x80000000u) ? ~u : (u | 0x80000000u);
}

// ---- e2[k] = sum_d embed[k][d]^2 ----
__global__ void e2_kernel(const float* __restrict__ embed, float* __restrict__ e2) {
    int k = blockIdx.x * blockDim.x + threadIdx.x;
    const float4* e = reinterpret_cast<const float4*>(embed + (size_t)k * DIM);
    float s = 0.f;
#pragma unroll
    for (int i = 0; i < DIM / 4; ++i) {
        float4 v = e[i];
        s = fmaf(v.x, v.x, s);
        s = fmaf(v.y, v.y, s);
        s = fmaf(v.z, v.z, s);
        s = fmaf(v.w, v.w, s);
    }
    e2[k] = s;
}

// ---- distance + argmin: block = 64 rows x all codes, chunked by 64 ----
// No atomics: running per-thread argmin across chunks, one LDS reduction at end.
__global__ __launch_bounds__(256, 4) void dist_argmin_kernel(
        const float* __restrict__ x, const float* __restrict__ embed,
        const float* __restrict__ e2,
        int* __restrict__ ind_ws, float* __restrict__ ind_out) {
    __shared__ __align__(16) float xs[BM * XST];   // 17408 B, staged once
    __shared__ __align__(16) float es[CK * EST];   // 17408 B, per chunk (reused as red)
    __shared__ __align__(16) float es2[CK];        // 256 B
    // total ~35 KB -> 4 blocks/CU

    const int tid = threadIdx.x;
    const int tx = tid & 15;        // col group: cols tx + 16j
    const int ty = tid >> 4;        // row group: rows ty*4 + i
    const int r0 = blockIdx.x * BM;

    // ---- stage x tile once: thread -> row tid>>2, float4s (q, q+4, q+8, q+12)
    {
        int row = tid >> 2, q = tid & 3;
        const float4* src = (const float4*)(x + (size_t)(r0 + row) * DIM);
        float4 a = src[q], b = src[q + 4], c = src[q + 8], d = src[q + 12];
        *(float4*)(&xs[row * XST + 4 * q])        = a;
        *(float4*)(&xs[row * XST + 4 * (q + 4)])  = b;
        *(float4*)(&xs[row * XST + 4 * (q + 8)])  = c;
        *(float4*)(&xs[row * XST + 4 * (q + 12)]) = d;
    }

    float bsc[4]  = {3.4e38f, 3.4e38f, 3.4e38f, 3.4e38f};
    int   bcol[4] = {0, 0, 0, 0};

    // ---- prefetch chunk 0 into registers
    const int prow = tid >> 2, pq = tid & 3;
    float4 pv0, pv1, pv2, pv3, p2;
    {
        const float4* src = (const float4*)(embed + (size_t)prow * DIM);
        pv0 = src[pq]; pv1 = src[pq + 4]; pv2 = src[pq + 8]; pv3 = src[pq + 12];
    }
    if (tid < 16) p2 = *(const float4*)(e2 + tid * 4);

    for (int ch = 0; ch < NCHUNK; ++ch) {
        __syncthreads();            // es free (prev compute / x-stage done)
        *(float4*)(&es[prow * EST + 4 * pq])        = pv0;
        *(float4*)(&es[prow * EST + 4 * (pq + 4)])  = pv1;
        *(float4*)(&es[prow * EST + 4 * (pq + 8)])  = pv2;
        *(float4*)(&es[prow * EST + 4 * (pq + 12)]) = pv3;
        if (tid < 16) *(float4*)(&es2[tid * 4]) = p2;
        __syncthreads();            // es ready
        if (ch + 1 < NCHUNK) {      // prefetch next chunk (overlaps compute)
            const float4* src =
                (const float4*)(embed + (size_t)((ch + 1) * CK + prow) * DIM);
            pv0 = src[pq]; pv1 = src[pq + 4]; pv2 = src[pq + 8]; pv3 = src[pq + 12];
            if (tid < 16) p2 = *(const float4*)(e2 + (ch + 1) * CK + tid * 4);
        }

        float acc[4][4];
#pragma unroll
        for (int i = 0; i < 4; ++i)
#pragma unroll
            for (int j = 0; j < 4; ++j) acc[i][j] = 0.f;

#pragma unroll
        for (int dd = 0; dd < DIM; dd += 4) {
            float4 xf[4], ef[4];
#pragma unroll
            for (int i = 0; i < 4; ++i)           // 16-lane broadcast reads
                xf[i] = *(const float4*)(&xs[(ty * 4 + i) * XST + dd]);
#pragma unroll
            for (int j = 0; j < 4; ++j)           // 16 distinct addrs, 2-way banks
                ef[j] = *(const float4*)(&es[(tx + 16 * j) * EST + dd]);
#pragma unroll
            for (int i = 0; i < 4; ++i)
#pragma unroll
                for (int j = 0; j < 4; ++j) {
                    acc[i][j] = fmaf(xf[i].x, ef[j].x, acc[i][j]);
                    acc[i][j] = fmaf(xf[i].y, ef[j].y, acc[i][j]);
                    acc[i][j] = fmaf(xf[i].z, ef[j].z, acc[i][j]);
                    acc[i][j] = fmaf(xf[i].w, ef[j].w, acc[i][j]);
                }
        }

        const int c0 = ch * CK;
#pragma unroll
        for (int j = 0; j < 4; ++j) {
            float e2v = es2[tx + 16 * j];
            int c = c0 + tx + 16 * j;
#pragma unroll
            for (int i = 0; i < 4; ++i) {
                float sc = fmaf(-2.f, acc[i][j], e2v);  // ||x||^2 dropped
                if (sc < bsc[i]) { bsc[i] = sc; bcol[i] = c; }  // strict <: first min
            }
        }
    }

    // ---- cross-tx reduction (reuse es as u64[64][16]) ----
    __syncthreads();
    unsigned long long* red = (unsigned long long*)es;
#pragma unroll
    for (int i = 0; i < 4; ++i) {
        unsigned long long key =
            ((unsigned long long)fkey(bsc[i]) << 32) | (unsigned int)bcol[i];
        red[(ty * 4 + i) * 16 + tx] = key;
    }
    __syncthreads();
    if (tid < BM) {
        unsigned long long b = red[tid * 16];
#pragma unroll
        for (int t = 1; t < 16; ++t) {
            unsigned long long v = red[tid * 16 + t];
            if (v < b) b = v;   // equal scores -> lower col wins (matches ref)
        }
        int k = (int)(b & 0xFFFFFFFFull);
        ind_ws[r0 + tid] = k;
        ind_out[r0 + tid] = (float)k;
    }
}

// ---- gather quantize + scatter stats (one wave = one row) ----
__global__ void scatter_kernel(const float* __restrict__ x,
                               const float* __restrict__ embed,
                               const int* __restrict__ ind,
                               float* __restrict__ quant,
                               float* __restrict__ cs,
                               float* __restrict__ esum) {
    const int t = blockIdx.x * blockDim.x + threadIdx.x;  // over N*DIM
    const int row = t >> 6;
    const int d = t & 63;
    const int k = ind[row];                      // broadcast within wave
    quant[t] = embed[(size_t)k * DIM + d];       // coalesced gather
    atomicAdd(&esum[(size_t)k * DIM + d], x[t]); // fp32 device-scope atomic
    if (d == 0) atomicAdd(&cs[k], 1.0f);         // one atomic per wave
}

extern "C" void kernel_launch(void* const* d_in, const int* in_sizes, int n_in,
                              void* d_out, int out_size, void* d_ws, size_t ws_size,
                              hipStream_t stream) {
    const float* x     = (const float*)d_in[0];
    const float* embed = (const float*)d_in[1];

    float* out     = (float*)d_out;
    float* quant   = out;                              // [N, D]
    float* ind_out = out + (size_t)N_ROWS * DIM;       // [N] (as float)
    float* cs      = ind_out + N_ROWS;                 // [K]
    float* esum    = cs + K_CODES;                     // [K, D]

    // ws: e2 [K] | ind_ws [N]
    float* e2     = (float*)d_ws;
    int*   ind_ws = (int*)(e2 + K_CODES);

    hipMemsetAsync(cs, 0, (size_t)(K_CODES + K_CODES * DIM) * sizeof(float), stream);

    e2_kernel<<<K_CODES / 256, 256, 0, stream>>>(embed, e2);
    dist_argmin_kernel<<<N_ROWS / BM, 256, 0, stream>>>(
        x, embed, e2, ind_ws, ind_out);
    scatter_kernel<<<(size_t)N_ROWS * DIM / 256, 256, 0, stream>>>(
        x, embed, ind_ws, quant, cs, esum);
}

// Round 5
// 987.431 us; speedup vs baseline: 1.3820x; 1.3820x over previous
//
#include <hip/hip_runtime.h>

#define N_ROWS 131072
#define DIM 64
#define K_CODES 4096

#define BM 128                 // rows per block
#define BN 128                 // cols per chunk tile
#define NSPLIT 4               // col splits (grid.y)
#define CPS (K_CODES / NSPLIT) // 1024 cols per split
#define NCH (CPS / BN)         // 8 chunks per block
#define DH 32                  // dims staged per half
#define XST 68                 // x LDS stride: (4*ty+dd)%32 distinct -> conflict-free
#define EST 36                 // e LDS stride: (4*tx+dd)%32 2-way -> free (m136)

// order-preserving float -> uint32 (min over keys == min over floats; scores finite)
__device__ inline unsigned int fkey(float f) {
    unsigned int u = __float_as_uint(f);
    return (u & 0x80000000u) ? ~u : (u | 0x80000000u);
}

// ---- e2[k] = sum_d embed[k][d]^2 ----
__global__ void e2_kernel(const float* __restrict__ embed, float* __restrict__ e2) {
    int k = blockIdx.x * blockDim.x + threadIdx.x;
    const float4* e = reinterpret_cast<const float4*>(embed + (size_t)k * DIM);
    float s = 0.f;
#pragma unroll
    for (int i = 0; i < DIM / 4; ++i) {
        float4 v = e[i];
        s = fmaf(v.x, v.x, s);
        s = fmaf(v.y, v.y, s);
        s = fmaf(v.z, v.z, s);
        s = fmaf(v.w, v.w, s);
    }
    e2[k] = s;
}

// ---- distance + argmin over one col-split ----
// 128x128 tile, 8x8/thread, x staged once, e staged per 32-dim half.
// No register-held prefetch (R4 spilled 2 GB of scratch). No atomics.
__global__ __launch_bounds__(256, 3) void dist_argmin_kernel(
        const float* __restrict__ x, const float* __restrict__ embed,
        const float* __restrict__ e2, unsigned long long* __restrict__ pk_ws) {
    __shared__ __align__(16) float xs[BM * XST];  // 34816 B
    __shared__ __align__(16) float es[BN * EST];  // 18432 B  (total 53248 -> 3 blk/CU)

    const int tid = threadIdx.x;
    const int tx = tid & 15;
    const int ty = tid >> 4;
    const int r0 = blockIdx.x * BM;
    const int cbase = blockIdx.y * CPS;

    // ---- stage x tile once (coalesced-ish; runs once, cost amortized) ----
    {
        const int row = tid >> 2;   // 0..63
        const int f0 = tid & 3;     // 0..3
#pragma unroll
        for (int p = 0; p < 2; ++p) {
            const int rr = row + p * 64;
            const float4* src = (const float4*)(x + (size_t)(r0 + rr) * DIM);
#pragma unroll
            for (int g = 0; g < 4; ++g) {
                const int f4 = f0 + 4 * g;
                *(float4*)(&xs[rr * XST + 4 * f4]) = src[f4];
            }
        }
    }

    float bsc[8];
    int bcol[8];
#pragma unroll
    for (int i = 0; i < 8; ++i) { bsc[i] = 3.4e38f; bcol[i] = 0; }

    for (int ch = 0; ch < NCH; ++ch) {
        const int c0 = cbase + ch * BN;
        float acc[8][8];
#pragma unroll
        for (int i = 0; i < 8; ++i)
#pragma unroll
            for (int j = 0; j < 8; ++j) acc[i][j] = 0.f;

#pragma unroll
        for (int h = 0; h < 2; ++h) {
            const int d0 = h * DH;
            __syncthreads();   // prior readers of es are done
            {  // stage e[c0:+128][d0:+32]: 8 contiguous 128B runs per wave
                const int colg = tid >> 3;  // 0..31
                const int f4 = tid & 7;     // 0..7
#pragma unroll
                for (int p = 0; p < 4; ++p) {
                    const int col = colg + 32 * p;
                    float4 v = *(const float4*)(embed + (size_t)(c0 + col) * DIM + d0 + 4 * f4);
                    *(float4*)(&es[col * EST + 4 * f4]) = v;
                }
            }
            __syncthreads();   // es ready

            for (int dd = 0; dd < DH; dd += 4) {
                float4 xf[8];
#pragma unroll
                for (int i = 0; i < 8; ++i)   // broadcast reads (16 lanes/addr)
                    xf[i] = *(const float4*)(&xs[(ty + 16 * i) * XST + d0 + dd]);
#pragma unroll
                for (int jj = 0; jj < 8; jj += 4) {
                    float4 ef[4];
#pragma unroll
                    for (int j = 0; j < 4; ++j)  // 16 addrs, 2-way banks = free
                        ef[j] = *(const float4*)(&es[(tx + 16 * (jj + j)) * EST + dd]);
#pragma unroll
                    for (int i = 0; i < 8; ++i)
#pragma unroll
                        for (int j = 0; j < 4; ++j) {
                            acc[i][jj + j] = fmaf(xf[i].x, ef[j].x, acc[i][jj + j]);
                            acc[i][jj + j] = fmaf(xf[i].y, ef[j].y, acc[i][jj + j]);
                            acc[i][jj + j] = fmaf(xf[i].z, ef[j].z, acc[i][jj + j]);
                            acc[i][jj + j] = fmaf(xf[i].w, ef[j].w, acc[i][jj + j]);
                        }
                }
            }
        }

        // epilogue: score = e2[c] - 2*dot (||x||^2 dropped); e2 is L1-hot (16 KB)
#pragma unroll
        for (int j = 0; j < 8; ++j) {
            const int c = c0 + tx + 16 * j;
            const float e2v = e2[c];
#pragma unroll
            for (int i = 0; i < 8; ++i) {
                float sc = fmaf(-2.f, acc[i][j], e2v);
                if (sc < bsc[i]) { bsc[i] = sc; bcol[i] = c; }  // strict <: first min
            }
        }
    }

    // ---- block reduction across the 16 tx sharing each row (reuse xs) ----
    __syncthreads();
    unsigned long long* red = (unsigned long long*)xs;  // [128][16] u64 = 16 KB
#pragma unroll
    for (int i = 0; i < 8; ++i) {
        unsigned long long key =
            ((unsigned long long)fkey(bsc[i]) << 32) | (unsigned int)bcol[i];
        red[(ty + 16 * i) * 16 + tx] = key;
    }
    __syncthreads();
    if (tid < BM) {
        unsigned long long b = red[tid * 16];
#pragma unroll
        for (int t = 1; t < 16; ++t) {
            unsigned long long v = red[tid * 16 + t];
            if (v < b) b = v;
        }
        pk_ws[(size_t)blockIdx.y * N_ROWS + r0 + tid] = b;
    }
}

// ---- merge NSPLIT per-split candidates (deterministic, no atomics) ----
__global__ void merge_kernel(const unsigned long long* __restrict__ pk_ws,
                             int* __restrict__ ind_ws,
                             float* __restrict__ ind_out) {
    const int row = blockIdx.x * blockDim.x + threadIdx.x;
    unsigned long long b = pk_ws[row];
#pragma unroll
    for (int s = 1; s < NSPLIT; ++s) {
        unsigned long long v = pk_ws[(size_t)s * N_ROWS + row];
        if (v < b) b = v;  // equal scores -> lower col wins (key embeds col)
    }
    const int k = (int)(b & 0xFFFFFFFFull);
    ind_ws[row] = k;
    ind_out[row] = (float)k;
}

// ---- gather quantize + scatter stats (one wave = one row) ----
__global__ void scatter_kernel(const float* __restrict__ x,
                               const float* __restrict__ embed,
                               const int* __restrict__ ind,
                               float* __restrict__ quant,
                               float* __restrict__ cs,
                               float* __restrict__ esum) {
    const int t = blockIdx.x * blockDim.x + threadIdx.x;  // over N*DIM
    const int row = t >> 6;
    const int d = t & 63;
    const int k = ind[row];                      // broadcast within wave
    quant[t] = embed[(size_t)k * DIM + d];       // coalesced gather
    atomicAdd(&esum[(size_t)k * DIM + d], x[t]); // fp32 device-scope atomic
    if (d == 0) atomicAdd(&cs[k], 1.0f);         // one atomic per wave
}

extern "C" void kernel_launch(void* const* d_in, const int* in_sizes, int n_in,
                              void* d_out, int out_size, void* d_ws, size_t ws_size,
                              hipStream_t stream) {
    const float* x     = (const float*)d_in[0];
    const float* embed = (const float*)d_in[1];

    float* out     = (float*)d_out;
    float* quant   = out;                              // [N, D]
    float* ind_out = out + (size_t)N_ROWS * DIM;       // [N] (as float)
    float* cs      = ind_out + N_ROWS;                 // [K]
    float* esum    = cs + K_CODES;                     // [K, D]

    // ws: e2 [K] | pad to 8B | pk_ws [NSPLIT*N] u64 | ind_ws [N]
    float* e2 = (float*)d_ws;
    unsigned long long* pk_ws = (unsigned long long*)((char*)d_ws + 8192 * sizeof(float));
    int* ind_ws = (int*)(pk_ws + (size_t)NSPLIT * N_ROWS);

    hipMemsetAsync(cs, 0, (size_t)(K_CODES + K_CODES * DIM) * sizeof(float), stream);

    e2_kernel<<<K_CODES / 256, 256, 0, stream>>>(embed, e2);
    dist_argmin_kernel<<<dim3(N_ROWS / BM, NSPLIT), 256, 0, stream>>>(
        x, embed, e2, pk_ws);
    merge_kernel<<<N_ROWS / 256, 256, 0, stream>>>(pk_ws, ind_ws, ind_out);
    scatter_kernel<<<(size_t)N_ROWS * DIM / 256, 256, 0, stream>>>(
        x, embed, ind_ws, quant, cs, esum);
}

// Round 6
// 477.003 us; speedup vs baseline: 2.8609x; 2.0701x over previous
//
#include <hip/hip_runtime.h>

#define N_ROWS 131072
#define DIM 64
#define K_CODES 4096
#define BROWS 256            // rows per block = 4 waves x 64
#define CK 64                // cols per chunk
#define NCH (K_CODES / CK)   // 64 chunks
#define EST 72               // LDS bf16 stride (64 + 8 pad) -> bank-balanced frags
#define EPS 0.015625f        // flag margin: >=15x the bf16x3 numeric error bound

typedef __attribute__((ext_vector_type(8))) short short8;
typedef __attribute__((ext_vector_type(4))) float f32x4;

__device__ inline unsigned short bf16rn(float f) {      // round-nearest-even
    unsigned int u = __float_as_uint(f);
    u += 0x7FFFu + ((u >> 16) & 1u);
    return (unsigned short)(u >> 16);
}
// order-preserving float -> uint32 (finite scores)
__device__ inline unsigned int fkey(float f) {
    unsigned int u = __float_as_uint(f);
    return (u & 0x80000000u) ? ~u : (u | 0x80000000u);
}

// ---- e2[k] = sum_d embed[k][d]^2 (exact fp32) ----
__global__ void e2_kernel(const float* __restrict__ embed, float* __restrict__ e2) {
    int k = blockIdx.x * blockDim.x + threadIdx.x;
    const float4* e = reinterpret_cast<const float4*>(embed + (size_t)k * DIM);
    float s = 0.f;
#pragma unroll
    for (int i = 0; i < DIM / 4; ++i) {
        float4 v = e[i];
        s = fmaf(v.x, v.x, s);
        s = fmaf(v.y, v.y, s);
        s = fmaf(v.z, v.z, s);
        s = fmaf(v.w, v.w, s);
    }
    e2[k] = s;
}

// ---- MFMA distance + fused top-2 argmin ----
// Wave = 64 rows, A (xh,xl frags) in registers for the whole sweep.
// acc = xh*eh + xh*el + xl*eh (bf16x3), score = e2 - 2*acc.
__global__ __launch_bounds__(256, 2) void dist_argmin_kernel(
        const float* __restrict__ x, const float* __restrict__ embed,
        const float* __restrict__ e2g, int* __restrict__ ind_ws,
        float* __restrict__ ind_out, int* __restrict__ cnt,
        int* __restrict__ list) {
    __shared__ unsigned short esh[CK * EST];   // 9216 B
    __shared__ unsigned short esl[CK * EST];   // 9216 B
    __shared__ float e2s[CK];

    const int tid  = threadIdx.x;
    const int l15  = tid & 15;
    const int quad = (tid >> 4) & 3;
    const int wave = tid >> 6;
    const int r0w  = blockIdx.x * BROWS + wave * 64;

    // A-frags: A[m=l15][k=quad*8+j] per 16x16x32; rows 16i+l15, k-windows 32s+8q
    short8 ah[4][2], al[4][2];
#pragma unroll
    for (int i = 0; i < 4; ++i)
#pragma unroll
        for (int s = 0; s < 2; ++s) {
            const float* xp = x + (size_t)(r0w + 16 * i + l15) * DIM + 32 * s + 8 * quad;
            float4 f0 = *(const float4*)xp;
            float4 f1 = *(const float4*)(xp + 4);
            float w[8] = {f0.x, f0.y, f0.z, f0.w, f1.x, f1.y, f1.z, f1.w};
            short8 h, l;
#pragma unroll
            for (int j = 0; j < 8; ++j) {
                unsigned short hb = bf16rn(w[j]);
                float hf = __uint_as_float(((unsigned int)hb) << 16);
                h[j] = (short)hb;
                l[j] = (short)bf16rn(w[j] - hf);
            }
            ah[i][s] = h;
            al[i][s] = l;
        }

    float s1[16], s2[16];
    int c1[16];
#pragma unroll
    for (int t = 0; t < 16; ++t) { s1[t] = 3.4e38f; s2[t] = 3.4e38f; c1[t] = 0; }

    for (int ch = 0; ch < NCH; ++ch) {
        const int c0 = ch * CK;
        __syncthreads();   // prior chunk's frag reads done
        {   // stage eh/el (convert fp32 -> bf16 hi/lo on the fly)
            const int col = tid >> 2;
            const int dq  = (tid & 3) * 16;
            const float* ep = embed + (size_t)(c0 + col) * DIM + dq;
            float4 a = *(const float4*)ep,       b = *(const float4*)(ep + 4),
                   c = *(const float4*)(ep + 8), d = *(const float4*)(ep + 12);
            float w[16] = {a.x, a.y, a.z, a.w, b.x, b.y, b.z, b.w,
                           c.x, c.y, c.z, c.w, d.x, d.y, d.z, d.w};
            unsigned short hb[16], lb[16];
#pragma unroll
            for (int j = 0; j < 16; ++j) {
                hb[j] = bf16rn(w[j]);
                float hf = __uint_as_float(((unsigned int)hb[j]) << 16);
                lb[j] = bf16rn(w[j] - hf);
            }
            *(uint4*)(&esh[col * EST + dq])     = *(uint4*)(hb);
            *(uint4*)(&esh[col * EST + dq + 8]) = *(uint4*)(hb + 8);
            *(uint4*)(&esl[col * EST + dq])     = *(uint4*)(lb);
            *(uint4*)(&esl[col * EST + dq + 8]) = *(uint4*)(lb + 8);
            if (tid < CK) e2s[tid] = e2g[c0 + tid];
        }
        __syncthreads();   // es ready

        f32x4 acc[4][4];
#pragma unroll
        for (int i = 0; i < 4; ++i)
#pragma unroll
            for (int j = 0; j < 4; ++j) acc[i][j] = (f32x4){0.f, 0.f, 0.f, 0.f};

#pragma unroll
        for (int j = 0; j < 4; ++j) {
            const int cb = (16 * j + l15) * EST + 8 * quad;   // B[n=l15][k=8q+j]
            short8 bh0 = *(const short8*)(&esh[cb]);
            short8 bh1 = *(const short8*)(&esh[cb + 32]);
            short8 bl0 = *(const short8*)(&esl[cb]);
            short8 bl1 = *(const short8*)(&esl[cb + 32]);
#pragma unroll
            for (int i = 0; i < 4; ++i) {
                f32x4 a = acc[i][j];
                a = __builtin_amdgcn_mfma_f32_16x16x32_bf16(ah[i][0], bh0, a, 0, 0, 0);
                a = __builtin_amdgcn_mfma_f32_16x16x32_bf16(ah[i][1], bh1, a, 0, 0, 0);
                a = __builtin_amdgcn_mfma_f32_16x16x32_bf16(ah[i][0], bl0, a, 0, 0, 0);
                a = __builtin_amdgcn_mfma_f32_16x16x32_bf16(ah[i][1], bl1, a, 0, 0, 0);
                a = __builtin_amdgcn_mfma_f32_16x16x32_bf16(al[i][0], bh0, a, 0, 0, 0);
                a = __builtin_amdgcn_mfma_f32_16x16x32_bf16(al[i][1], bh1, a, 0, 0, 0);
                acc[i][j] = a;
            }
        }

        // epilogue: C/D layout col=l15, row=quad*4+r (per 16-tile i)
#pragma unroll
        for (int j = 0; j < 4; ++j) {
            const int c = c0 + 16 * j + l15;
            const float e2v = e2s[16 * j + l15];
#pragma unroll
            for (int i = 0; i < 4; ++i)
#pragma unroll
                for (int r = 0; r < 4; ++r) {
                    float sc = fmaf(-2.f, acc[i][j][r], e2v);
                    const int st = i * 4 + r;
                    bool lt = sc < s1[st];
                    s2[st] = lt ? s1[st] : fminf(s2[st], sc);
                    c1[st] = lt ? c : c1[st];
                    s1[st] = lt ? sc : s1[st];
                }
        }
    }

    // butterfly top-2 merge across the 16 lanes (same quad) sharing each row
#pragma unroll
    for (int st = 0; st < 16; ++st) {
#pragma unroll
        for (int m = 1; m < 16; m <<= 1) {
            float os1 = __shfl_xor(s1[st], m, 64);
            float os2 = __shfl_xor(s2[st], m, 64);
            int   oc1 = __shfl_xor(c1[st], m, 64);
            bool take = (os1 < s1[st]) || (os1 == s1[st] && oc1 < c1[st]);
            float loser = take ? s1[st] : os1;
            s2[st] = fminf(fminf(s2[st], os2), loser);
            if (take) { s1[st] = os1; c1[st] = oc1; }
        }
    }
    if (l15 == 0) {
#pragma unroll
        for (int st = 0; st < 16; ++st) {
            const int i = st >> 2, r = st & 3;
            const int row = r0w + 16 * i + 4 * quad + r;
            ind_ws[row] = c1[st];
            ind_out[row] = (float)c1[st];
            if (s2[st] - s1[st] < EPS) {     // ambiguous under bf16x3 error
                int p = atomicAdd(cnt, 1);
                list[p] = row;
            }
        }
    }
}

// ---- exact fp32 re-solve for flagged rows (block per row, static grid) ----
__global__ void refine_kernel(const float* __restrict__ x,
                              const float* __restrict__ embed,
                              const float* __restrict__ e2g,
                              const int* __restrict__ cnt,
                              const int* __restrict__ list,
                              int* __restrict__ ind_ws,
                              float* __restrict__ ind_out) {
    __shared__ float xr[DIM];
    __shared__ unsigned long long red[256];
    const int tid = threadIdx.x;
    const int n = *cnt;
    for (int f = blockIdx.x; f < n; f += gridDim.x) {
        const int row = list[f];
        __syncthreads();
        if (tid < 16)
            ((float4*)xr)[tid] = ((const float4*)(x + (size_t)row * DIM))[tid];
        __syncthreads();
        unsigned long long best = ~0ull;
        for (int c = tid; c < K_CODES; c += 256) {
            const float4* ep = (const float4*)(embed + (size_t)c * DIM);
            float d0 = 0.f, d1 = 0.f, d2 = 0.f, d3 = 0.f;
#pragma unroll
            for (int q = 0; q < 16; ++q) {
                float4 ev = ep[q];
                d0 = fmaf(xr[4 * q + 0], ev.x, d0);
                d1 = fmaf(xr[4 * q + 1], ev.y, d1);
                d2 = fmaf(xr[4 * q + 2], ev.z, d2);
                d3 = fmaf(xr[4 * q + 3], ev.w, d3);
            }
            float sc = fmaf(-2.f, (d0 + d1) + (d2 + d3), e2g[c]);
            unsigned long long key =
                ((unsigned long long)fkey(sc) << 32) | (unsigned int)c;
            if (key < best) best = key;
        }
        red[tid] = best;
        __syncthreads();
        for (int w = 128; w > 0; w >>= 1) {
            if (tid < w && red[tid + w] < red[tid]) red[tid] = red[tid + w];
            __syncthreads();
        }
        if (tid == 0) {
            int k = (int)(red[0] & 0xFFFFFFFFull);
            ind_ws[row] = k;
            ind_out[row] = (float)k;
        }
    }
}

// ---- gather quantize + scatter stats (one wave = one row) ----
__global__ void scatter_kernel(const float* __restrict__ x,
                               const float* __restrict__ embed,
                               const int* __restrict__ ind,
                               float* __restrict__ quant,
                               float* __restrict__ cs,
                               float* __restrict__ esum) {
    const int t = blockIdx.x * blockDim.x + threadIdx.x;
    const int row = t >> 6;
    const int d = t & 63;
    const int k = ind[row];
    quant[t] = embed[(size_t)k * DIM + d];
    atomicAdd(&esum[(size_t)k * DIM + d], x[t]);
    if (d == 0) atomicAdd(&cs[k], 1.0f);
}

extern "C" void kernel_launch(void* const* d_in, const int* in_sizes, int n_in,
                              void* d_out, int out_size, void* d_ws, size_t ws_size,
                              hipStream_t stream) {
    const float* x     = (const float*)d_in[0];
    const float* embed = (const float*)d_in[1];

    float* out     = (float*)d_out;
    float* quant   = out;                            // [N, D]
    float* ind_out = out + (size_t)N_ROWS * DIM;     // [N] (as float)
    float* cs      = ind_out + N_ROWS;               // [K]
    float* esum    = cs + K_CODES;                   // [K, D]

    // ws: e2 [K] | cnt [4 ints] | list [N] | ind_ws [N]   (~1.1 MB)
    float* e2   = (float*)d_ws;
    int* cnt    = (int*)(e2 + K_CODES);
    int* list   = cnt + 4;
    int* ind_ws = list + N_ROWS;

    hipMemsetAsync(cs, 0, (size_t)(K_CODES + K_CODES * DIM) * sizeof(float), stream);
    hipMemsetAsync(cnt, 0, sizeof(int), stream);

    e2_kernel<<<K_CODES / 256, 256, 0, stream>>>(embed, e2);
    dist_argmin_kernel<<<N_ROWS / BROWS, 256, 0, stream>>>(
        x, embed, e2, ind_ws, ind_out, cnt, list);
    refine_kernel<<<256, 256, 0, stream>>>(x, embed, e2, cnt, list, ind_ws, ind_out);
    scatter_kernel<<<(size_t)N_ROWS * DIM / 256, 256, 0, stream>>>(
        x, embed, ind_ws, quant, cs, esum);
}